// Round 2
// baseline (1076.152 us; speedup 1.0000x reference)
//
#include <hip/hip_runtime.h>
#include <hip/hip_bf16.h>

// ---------------------------------------------------------------------------
// CrossAttention: x,y + sincos-PE (flat add), two 3x3 conv stacks (q,k),
// softmax(q k^T * scale) @ v  with v scalar per key.
// Round 2: all-f32 I/O (device buffers are f32; bf16 is only the grading tol).
// ---------------------------------------------------------------------------

// ---- PE table: pe[p][2i] = sin(p*div_i), pe[p][2i+1] = cos(p*div_i) -------
__global__ void pe_fill_k(float* __restrict__ pe)
{
    int idx = blockIdx.x * 256 + threadIdx.x;   // 4096*64 (p, i) pairs
    int p = idx >> 6;
    int i = idx & 63;
    // -ln(10000)/128 = -0.07195578415606394
    float div = expf(-0.07195578415606394f * (float)(2 * i));
    float arg = (float)p * div;
    pe[(p << 7) + 2 * i]     = sinf(arg);
    pe[(p << 7) + 2 * i + 1] = cosf(arg);
}

// ---- flat PE add: out[b*N + f] = in[b*N+f] + pe[f & mask] -----------------
__global__ void pe_add_k(const float* __restrict__ in,
                         const float* __restrict__ pe,
                         float* __restrict__ out, int perBatchMask, int total)
{
    int idx = blockIdx.x * 256 + threadIdx.x;
    if (idx >= total) return;
    int f = idx & perBatchMask;                 // perBatch is a power of 2
    out[idx] = in[idx] + pe[f];
}

// ---- direct 3x3 conv, SAME padding, NCHW, one block per (b, co) -----------
// Threads: 256.  Each thread owns a vertical run of RUN pixels in one column.
// Per ci: stage full input plane in LDS (float4), then 3*(RUN+2) LDS reads
// feed 9*RUN FMAs (rolling 3-wide row window).
template<int WW, int HH, int RUN>
__global__ __launch_bounds__(256)
void conv3x3_k(const float* __restrict__ in, const float* __restrict__ wt,
               const float* __restrict__ bias, float* __restrict__ out,
               int do_relu)
{
    constexpr int PIX = WW * HH;
    __shared__ float tile[PIX];

    const int b   = blockIdx.x >> 7;
    const int co  = blockIdx.x & 127;
    const int tid = threadIdx.x;
    const int w   = tid % WW;
    const int h0  = (tid / WW) * RUN;

    const float* inb = in + (size_t)(b * 128) * PIX;
    const float* wco = wt + (size_t)co * 128 * 9;

    float acc[RUN];
    const float bv = bias[co];
#pragma unroll
    for (int a = 0; a < RUN; ++a) acc[a] = bv;

    for (int ci = 0; ci < 128; ++ci) {
        __syncthreads();
        const float4* src = (const float4*)(inb + ci * PIX);
        float4* dst = (float4*)tile;
        for (int t = tid; t < PIX / 4; t += 256) dst[t] = src[t];
        __syncthreads();

        float w9[9];
#pragma unroll
        for (int t = 0; t < 9; ++t) w9[t] = wco[ci * 9 + t];

#pragma unroll
        for (int ri = -1; ri <= RUN; ++ri) {
            int  r  = h0 + ri;
            bool rv = (r >= 0) && (r < HH);
            float lv  = (rv && w > 0)      ? tile[r * WW + w - 1] : 0.f;
            float cv  = rv                 ? tile[r * WW + w]     : 0.f;
            float rgv = (rv && w < WW - 1) ? tile[r * WW + w + 1] : 0.f;
            // input row r feeds output rows r-1 (kh=2), r (kh=1), r+1 (kh=0)
            if (ri >= 1)
                acc[ri - 1] += w9[6] * lv + w9[7] * cv + w9[8] * rgv;
            if (ri >= 0 && ri < RUN)
                acc[ri]     += w9[3] * lv + w9[4] * cv + w9[5] * rgv;
            if (ri + 1 < RUN)
                acc[ri + 1] += w9[0] * lv + w9[1] * cv + w9[2] * rgv;
        }
    }

    float* ob = out + ((size_t)(b * 128) + co) * PIX;
#pragma unroll
    for (int a = 0; a < RUN; ++a) {
        float v = acc[a];
        if (do_relu) v = fmaxf(v, 0.f);
        ob[(h0 + a) * WW + w] = v;
    }
}

// ---- flash attention: out[b,p] = sum_k exp(s)*v / sum_k exp(s) ------------
// Block: (b, 32 q-rows). Threads 256 = 8 row-groups (i) x 32 k-lanes (j).
// Thread (i,j): rows 4i..4i+3, keys {kt + j + 32*bb}. 4x4 register blocking,
// per-lane online softmax, final shfl_xor merge over the 32 j-lanes.
__global__ __launch_bounds__(256)
void attn_k(const float* __restrict__ q, const float* __restrict__ k,
            const float* __restrict__ v, float* __restrict__ out)
{
    constexpr int QT = 32, KT = 128;
    __shared__ float qs[QT][132];
    __shared__ float ks[KT][132];
    __shared__ float vsm[KT];

    const int b   = blockIdx.x >> 5;
    const int qt  = blockIdx.x & 31;
    const int tid = threadIdx.x;
    const int i   = tid >> 5;     // 0..7
    const int j   = tid & 31;     // 0..31

    const float* qb = q + ((size_t)b * 1024 + qt * QT) * 128;
    const float* kb = k + (size_t)b * 4096 * 128;
    const float* vb = v + (size_t)b * 4096;

    for (int t = tid; t < QT * 32; t += 256) {
        int r = t >> 5, c = (t & 31) << 2;
        *(float4*)&qs[r][c] = *(const float4*)(qb + r * 128 + c);
    }

    float m[4], num[4], den[4];
#pragma unroll
    for (int a = 0; a < 4; ++a) { m[a] = -1e30f; num[a] = 0.f; den[a] = 0.f; }

    const float scale = 0.08838834764831845f;   // 128^-0.5

    for (int kt = 0; kt < 4096; kt += KT) {
        __syncthreads();
        for (int t = tid; t < KT * 32; t += 256) {
            int r = t >> 5, c = (t & 31) << 2;
            *(float4*)&ks[r][c] = *(const float4*)(kb + (size_t)(kt + r) * 128 + c);
        }
        if (tid < KT) vsm[tid] = vb[kt + tid];
        __syncthreads();

        float4 acc[4][4];
#pragma unroll
        for (int a = 0; a < 4; ++a)
#pragma unroll
            for (int bb = 0; bb < 4; ++bb) acc[a][bb] = float4{0.f, 0.f, 0.f, 0.f};

        for (int c = 0; c < 128; c += 4) {
            float4 qv[4], kv[4];
#pragma unroll
            for (int a = 0; a < 4; ++a)  qv[a] = *(const float4*)&qs[4 * i + a][c];
#pragma unroll
            for (int bb = 0; bb < 4; ++bb) kv[bb] = *(const float4*)&ks[j + 32 * bb][c];
#pragma unroll
            for (int a = 0; a < 4; ++a)
#pragma unroll
                for (int bb = 0; bb < 4; ++bb) {
                    acc[a][bb].x += qv[a].x * kv[bb].x;
                    acc[a][bb].y += qv[a].y * kv[bb].y;
                    acc[a][bb].z += qv[a].z * kv[bb].z;
                    acc[a][bb].w += qv[a].w * kv[bb].w;
                }
        }

#pragma unroll
        for (int a = 0; a < 4; ++a) {
#pragma unroll
            for (int bb = 0; bb < 4; ++bb) {
                float4 t4 = acc[a][bb];
                float s  = (t4.x + t4.y + t4.z + t4.w) * scale;
                float vv = vsm[j + 32 * bb];
                float mn = fmaxf(m[a], s);
                float c0 = __expf(m[a] - mn);
                float c1 = __expf(s - mn);
                num[a] = num[a] * c0 + vv * c1;
                den[a] = den[a] * c0 + c1;
                m[a]   = mn;
            }
        }
    }

#pragma unroll
    for (int off = 16; off > 0; off >>= 1) {
#pragma unroll
        for (int a = 0; a < 4; ++a) {
            float mo = __shfl_xor(m[a], off);
            float no = __shfl_xor(num[a], off);
            float dd = __shfl_xor(den[a], off);
            float mn = fmaxf(m[a], mo);
            float c0 = __expf(m[a] - mn);
            float c1 = __expf(mo - mn);
            num[a] = num[a] * c0 + no * c1;
            den[a] = den[a] * c0 + dd * c1;
            m[a]   = mn;
        }
    }
    if (j == 0) {
#pragma unroll
        for (int a = 0; a < 4; ++a)
            out[(size_t)b * 1024 + qt * QT + 4 * i + a] = num[a] / den[a];
    }
}

// ---------------------------------------------------------------------------
extern "C" void kernel_launch(void* const* d_in, const int* in_sizes, int n_in,
                              void* d_out, int out_size, void* d_ws, size_t ws_size,
                              hipStream_t stream)
{
    const float* x   = (const float*)d_in[0];  // 8*128*32*32
    const float* y   = (const float*)d_in[1];  // 8*128*64*64
    const float* z   = (const float*)d_in[2];  // 8*1*64*64
    const float* wq1 = (const float*)d_in[3];
    const float* bq1 = (const float*)d_in[4];
    const float* wq2 = (const float*)d_in[5];
    const float* bq2 = (const float*)d_in[6];
    const float* wk1 = (const float*)d_in[7];
    const float* bk1 = (const float*)d_in[8];
    const float* wk2 = (const float*)d_in[9];
    const float* bk2 = (const float*)d_in[10];

    // f32 workspace layout (total 16,252,928 floats = 62 MiB)
    float* ws   = (float*)d_ws;
    float* pe   = ws;                  // 4096*128          =   524288
    float* xpe  = pe   +  524288;      // 8*128*1024        =  1048576
    float* ype  = xpe  + 1048576;      // 8*128*4096        =  4194304
    float* t1   = ype  + 4194304;      //                      1048576
    float* qbuf = t1   + 1048576;      //                      1048576
    float* t2   = qbuf + 1048576;      //                      4194304
    float* kbuf = t2   + 4194304;      //                      4194304

    pe_fill_k<<<1024, 256, 0, stream>>>(pe);
    pe_add_k<<<(1048576 + 255) / 256, 256, 0, stream>>>(x, pe, xpe, 131071, 1048576);
    pe_add_k<<<(4194304 + 255) / 256, 256, 0, stream>>>(y, pe, ype, 524287, 4194304);

    conv3x3_k<32, 32, 4 ><<<1024, 256, 0, stream>>>(xpe, wq1, bq1, t1,   1);
    conv3x3_k<32, 32, 4 ><<<1024, 256, 0, stream>>>(t1,  wq2, bq2, qbuf, 0);
    conv3x3_k<64, 64, 16><<<1024, 256, 0, stream>>>(ype, wk1, bk1, t2,   1);
    conv3x3_k<64, 64, 16><<<1024, 256, 0, stream>>>(t2,  wk2, bk2, kbuf, 0);

    attn_k<<<256, 256, 0, stream>>>(qbuf, kbuf, z, (float*)d_out);
}

// Round 3
// 404.281 us; speedup vs baseline: 2.6619x; 2.6619x over previous
//
#include <hip/hip_runtime.h>
#include <hip/hip_bf16.h>

typedef _Float16 f16x8 __attribute__((ext_vector_type(8)));
typedef _Float16 f16x4 __attribute__((ext_vector_type(4)));
typedef float    f32x4 __attribute__((ext_vector_type(4)));

// ---- PE table: pe[p*128 + 2i] = sin(p*div_i), [..+1] = cos ---------------
__global__ void pe_fill_k(float* __restrict__ pe)
{
    int idx = blockIdx.x * 256 + threadIdx.x;   // 4096*64 (p, i) pairs
    int p = idx >> 6;
    int i = idx & 63;
    float div = expf(-0.07195578415606394f * (float)(2 * i)); // -ln(1e4)/128
    float arg = (float)p * div;
    pe[(p << 7) + 2 * i]     = sinf(arg);
    pe[(p << 7) + 2 * i + 1] = cosf(arg);
}

// ---- PE add + NCHW f32 -> NHWC f16 transpose ------------------------------
// Block: one batch, 64-pixel tile, all 128 channels. LDS tile transpose.
__global__ __launch_bounds__(256)
void pe_tr_k(const float* __restrict__ x, const float* __restrict__ pe,
             _Float16* __restrict__ out, int PIX)
{
    __shared__ _Float16 t[64 * 136];
    const int tilesPerB = PIX >> 6;
    const int b  = blockIdx.x / tilesPerB;
    const int p0 = (blockIdx.x % tilesPerB) << 6;
    const int tid = threadIdx.x;
    const int c  = tid & 127;
    const int ph = (tid >> 7) << 5;              // 0 or 32

    const float* xr = x  + ((size_t)b * 128 + c) * PIX + p0 + ph;
    const float* pr = pe + (size_t)c * PIX + p0 + ph;
#pragma unroll
    for (int i = 0; i < 32; i += 4) {
        float4 xv = *(const float4*)(xr + i);
        float4 pv = *(const float4*)(pr + i);
        t[(ph + i + 0) * 136 + c] = (_Float16)(xv.x + pv.x);
        t[(ph + i + 1) * 136 + c] = (_Float16)(xv.y + pv.y);
        t[(ph + i + 2) * 136 + c] = (_Float16)(xv.z + pv.z);
        t[(ph + i + 3) * 136 + c] = (_Float16)(xv.w + pv.w);
    }
    __syncthreads();

    const int p  = tid >> 2;
    const int c0 = (tid & 3) << 5;
    _Float16* orow = out + ((size_t)b * PIX + p0 + p) * 128 + c0;
    uint4 v0 = *(const uint4*)&t[p * 136 + c0];
    uint4 v1 = *(const uint4*)&t[p * 136 + c0 + 8];
    uint4 v2 = *(const uint4*)&t[p * 136 + c0 + 16];
    uint4 v3 = *(const uint4*)&t[p * 136 + c0 + 24];
    ((uint4*)orow)[0] = v0; ((uint4*)orow)[1] = v1;
    ((uint4*)orow)[2] = v2; ((uint4*)orow)[3] = v3;
}

// ---- weight pack: OIHW f32 -> MFMA A-fragment-major f16 -------------------
// frag f = (tap*4 + cichunk)*8 + mtile ; elem (lane, i) = W[mtile*16 + (lane&15)]
//          [cichunk*32 + (lane>>4)*8 + i][tap]
__global__ void pack_w_k(const float* __restrict__ w, _Float16* __restrict__ out)
{
    int gid = blockIdx.x * 256 + threadIdx.x;    // 9*4*8*64 = 18432
    int f = gid >> 6, l = gid & 63;
    int t = f >> 5, cc = (f >> 3) & 3, m = f & 7;
    int co  = m * 16 + (l & 15);
    int ci0 = cc * 32 + (l >> 4) * 8;
    f16x8 pk;
#pragma unroll
    for (int i = 0; i < 8; ++i)
        pk[i] = (_Float16)w[(co * 128 + ci0 + i) * 9 + t];
    *(f16x8*)(out + (size_t)gid * 8) = pk;
}

// ---- implicit-GEMM 3x3 conv, MFMA 16x16x32 f16 ----------------------------
// In: NHWC f16. Out: NHWC f16 (+ReLU) or NCHW f32. Block: 1 batch x NROWS
// image rows x all 128 co. 4 waves: wave = 4 m-tiles x 2 n-tiles.
template<int WW, int HH, int NROWS, bool RELU, bool NCHW_OUT>
__global__ __launch_bounds__(256)
void conv_mfma_k(const _Float16* __restrict__ in, const _Float16* __restrict__ wp,
                 const float* __restrict__ bias, void* __restrict__ outv)
{
    constexpr int PIX   = WW * HH;
    constexpr int SLABS = NROWS + 2;
    constexpr int NTPR  = WW / 16;               // n-tiles per image row
    constexpr int LST   = 136;                   // LDS row stride (f16 elems)

    __shared__ _Float16 lds[SLABS * WW * LST];

    const int bx  = blockIdx.x;
    const int b   = bx / (HH / NROWS);
    const int h0  = (bx % (HH / NROWS)) * NROWS;
    const int tid = threadIdx.x;
    const int wid = tid >> 6, lane = tid & 63;
    const int l15 = lane & 15, lg = lane >> 4;

    // ---- stage SLABS input rows (zero-filled outside image) ----
    const _Float16* inb = in + (size_t)b * PIX * 128;
    constexpr int CHUNKS = SLABS * WW * 16;      // 16B chunks
    for (int cid = tid; cid < CHUNKS; cid += 256) {
        int s   = cid / (WW * 16);
        int rem = cid - s * (WW * 16);
        int w   = rem >> 4;
        int c8  = (rem & 15) * 8;
        int row = h0 - 1 + s;
        uint4 v = {0u, 0u, 0u, 0u};
        if (row >= 0 && row < HH)
            v = *(const uint4*)(inb + ((size_t)row * WW + w) * 128 + c8);
        *(uint4*)&lds[(s * WW + w) * LST + c8] = v;
    }
    __syncthreads();

    const int mbase = (wid >> 1) * 4;            // 4 m-tiles
    const int nbase = (wid & 1) * 2;             // 2 n-tiles

    f32x4 acc[4][2] = {};

    for (int cc = 0; cc < 4; ++cc) {
#pragma unroll
        for (int t = 0; t < 9; ++t) {
            const int dh = t / 3, dw = t % 3;
            f16x8 af[4];
#pragma unroll
            for (int mt = 0; mt < 4; ++mt) {
                int f = (t * 4 + cc) * 8 + (mbase + mt);
                af[mt] = *(const f16x8*)(wp + ((size_t)f * 64 + lane) * 8);
            }
            f16x8 bfr[2];
#pragma unroll
            for (int nt = 0; nt < 2; ++nt) {
                int ntile = nbase + nt;
                int nrow  = ntile / NTPR;
                int wbase = (ntile % NTPR) * 16;
                int slab  = nrow + dh;
                int wpix  = wbase + l15 + dw - 1;
                bool ok   = (unsigned)wpix < (unsigned)WW;
                int  wc   = ok ? wpix : 0;
                uint4 r = *(const uint4*)&lds[(slab * WW + wc) * LST + cc * 32 + lg * 8];
                if (!ok) r = uint4{0u, 0u, 0u, 0u};
                bfr[nt] = __builtin_bit_cast(f16x8, r);
            }
#pragma unroll
            for (int mt = 0; mt < 4; ++mt)
#pragma unroll
                for (int nt = 0; nt < 2; ++nt)
                    acc[mt][nt] = __builtin_amdgcn_mfma_f32_16x16x32_f16(
                        af[mt], bfr[nt], acc[mt][nt], 0, 0, 0);
        }
    }

    // ---- epilogue: bias (+ReLU), store ----
#pragma unroll
    for (int mt = 0; mt < 4; ++mt) {
        int co = (mbase + mt) * 16 + lg * 4;
        float b0 = bias[co], b1 = bias[co + 1], b2 = bias[co + 2], b3 = bias[co + 3];
#pragma unroll
        for (int nt = 0; nt < 2; ++nt) {
            int ntile = nbase + nt;
            int nrow  = ntile / NTPR;
            int wbase = (ntile % NTPR) * 16;
            int p     = (h0 + nrow) * WW + wbase + l15;
            float v0 = acc[mt][nt][0] + b0;
            float v1 = acc[mt][nt][1] + b1;
            float v2 = acc[mt][nt][2] + b2;
            float v3 = acc[mt][nt][3] + b3;
            if (RELU) {
                v0 = fmaxf(v0, 0.f); v1 = fmaxf(v1, 0.f);
                v2 = fmaxf(v2, 0.f); v3 = fmaxf(v3, 0.f);
            }
            if (NCHW_OUT) {
                float* ob = (float*)outv + ((size_t)(b * 128 + co)) * PIX + p;
                ob[0]              = v0;
                ob[(size_t)PIX]    = v1;
                ob[(size_t)2*PIX]  = v2;
                ob[(size_t)3*PIX]  = v3;
            } else {
                _Float16* ob = (_Float16*)outv + ((size_t)b * PIX + p) * 128 + co;
                f16x4 pk = {(_Float16)v0, (_Float16)v1, (_Float16)v2, (_Float16)v3};
                *(f16x4*)ob = pk;
            }
        }
    }
}

// ---- flash attention (f32, unchanged from round 2) ------------------------
__global__ __launch_bounds__(256)
void attn_k(const float* __restrict__ q, const float* __restrict__ k,
            const float* __restrict__ v, float* __restrict__ out)
{
    constexpr int QT = 32, KT = 128;
    __shared__ float qs[QT][132];
    __shared__ float ks[KT][132];
    __shared__ float vsm[KT];

    const int b   = blockIdx.x >> 5;
    const int qt  = blockIdx.x & 31;
    const int tid = threadIdx.x;
    const int i   = tid >> 5;
    const int j   = tid & 31;

    const float* qb = q + ((size_t)b * 1024 + qt * QT) * 128;
    const float* kb = k + (size_t)b * 4096 * 128;
    const float* vb = v + (size_t)b * 4096;

    for (int t = tid; t < QT * 32; t += 256) {
        int r = t >> 5, c = (t & 31) << 2;
        *(float4*)&qs[r][c] = *(const float4*)(qb + r * 128 + c);
    }

    float m[4], num[4], den[4];
#pragma unroll
    for (int a = 0; a < 4; ++a) { m[a] = -1e30f; num[a] = 0.f; den[a] = 0.f; }

    const float scale = 0.08838834764831845f;

    for (int kt = 0; kt < 4096; kt += KT) {
        __syncthreads();
        for (int t = tid; t < KT * 32; t += 256) {
            int r = t >> 5, c = (t & 31) << 2;
            *(float4*)&ks[r][c] = *(const float4*)(kb + (size_t)(kt + r) * 128 + c);
        }
        if (tid < KT) vsm[tid] = vb[kt + tid];
        __syncthreads();

        float4 acc[4][4];
#pragma unroll
        for (int a = 0; a < 4; ++a)
#pragma unroll
            for (int bb = 0; bb < 4; ++bb) acc[a][bb] = float4{0.f, 0.f, 0.f, 0.f};

        for (int c = 0; c < 128; c += 4) {
            float4 qv[4], kv[4];
#pragma unroll
            for (int a = 0; a < 4; ++a)  qv[a] = *(const float4*)&qs[4 * i + a][c];
#pragma unroll
            for (int bb = 0; bb < 4; ++bb) kv[bb] = *(const float4*)&ks[j + 32 * bb][c];
#pragma unroll
            for (int a = 0; a < 4; ++a)
#pragma unroll
                for (int bb = 0; bb < 4; ++bb) {
                    acc[a][bb].x += qv[a].x * kv[bb].x;
                    acc[a][bb].y += qv[a].y * kv[bb].y;
                    acc[a][bb].z += qv[a].z * kv[bb].z;
                    acc[a][bb].w += qv[a].w * kv[bb].w;
                }
        }

#pragma unroll
        for (int a = 0; a < 4; ++a) {
#pragma unroll
            for (int bb = 0; bb < 4; ++bb) {
                float4 t4 = acc[a][bb];
                float s  = (t4.x + t4.y + t4.z + t4.w) * scale;
                float vv = vsm[j + 32 * bb];
                float mn = fmaxf(m[a], s);
                float c0 = __expf(m[a] - mn);
                float c1 = __expf(s - mn);
                num[a] = num[a] * c0 + vv * c1;
                den[a] = den[a] * c0 + c1;
                m[a]   = mn;
            }
        }
    }

#pragma unroll
    for (int off = 16; off > 0; off >>= 1) {
#pragma unroll
        for (int a = 0; a < 4; ++a) {
            float mo = __shfl_xor(m[a], off);
            float no = __shfl_xor(num[a], off);
            float dd = __shfl_xor(den[a], off);
            float mn = fmaxf(m[a], mo);
            float c0 = __expf(m[a] - mn);
            float c1 = __expf(mo - mn);
            num[a] = num[a] * c0 + no * c1;
            den[a] = den[a] * c0 + dd * c1;
            m[a]   = mn;
        }
    }
    if (j == 0) {
#pragma unroll
        for (int a = 0; a < 4; ++a)
            out[(size_t)b * 1024 + qt * QT + 4 * i + a] = num[a] / den[a];
    }
}

// ---------------------------------------------------------------------------
extern "C" void kernel_launch(void* const* d_in, const int* in_sizes, int n_in,
                              void* d_out, int out_size, void* d_ws, size_t ws_size,
                              hipStream_t stream)
{
    const float* x   = (const float*)d_in[0];   // 8*128*32*32
    const float* y   = (const float*)d_in[1];   // 8*128*64*64
    const float* z   = (const float*)d_in[2];   // 8*1*64*64
    const float* wq1 = (const float*)d_in[3];
    const float* bq1 = (const float*)d_in[4];
    const float* wq2 = (const float*)d_in[5];
    const float* bq2 = (const float*)d_in[6];
    const float* wk1 = (const float*)d_in[7];
    const float* bk1 = (const float*)d_in[8];
    const float* wk2 = (const float*)d_in[9];
    const float* bk2 = (const float*)d_in[10];

    char* w8 = (char*)d_ws;
    float*    pe   = (float*)(w8);                         // 2 MB
    float*    qbuf = (float*)(w8 + (2u  << 20));           // 4 MB  NCHW f32
    float*    kbuf = (float*)(w8 + (6u  << 20));           // 16 MB NCHW f32
    _Float16* xpe  = (_Float16*)(w8 + (22u << 20));        // 2 MB  NHWC f16
    _Float16* ype  = (_Float16*)(w8 + (24u << 20));        // 8 MB  NHWC f16
    _Float16* t1   = (_Float16*)(w8 + (32u << 20));        // 2 MB  NHWC f16
    _Float16* t2   = (_Float16*)(w8 + (34u << 20));        // 8 MB  NHWC f16
    _Float16* wq1p = (_Float16*)(w8 + (42u << 20));        // 288 KB each
    _Float16* wq2p = wq1p + 147456;
    _Float16* wk1p = wq2p + 147456;
    _Float16* wk2p = wk1p + 147456;

    pe_fill_k<<<1024, 256, 0, stream>>>(pe);
    pe_tr_k<<<128, 256, 0, stream>>>(x, pe, xpe, 1024);
    pe_tr_k<<<512, 256, 0, stream>>>(y, pe, ype, 4096);

    pack_w_k<<<72, 256, 0, stream>>>(wq1, wq1p);
    pack_w_k<<<72, 256, 0, stream>>>(wq2, wq2p);
    pack_w_k<<<72, 256, 0, stream>>>(wk1, wk1p);
    pack_w_k<<<72, 256, 0, stream>>>(wk2, wk2p);

    conv_mfma_k<32, 32, 2, true,  false><<<128, 256, 0, stream>>>(xpe, wq1p, bq1, t1);
    conv_mfma_k<32, 32, 2, false, true ><<<128, 256, 0, stream>>>(t1,  wq2p, bq2, qbuf);
    conv_mfma_k<64, 64, 1, true,  false><<<512, 256, 0, stream>>>(ype, wk1p, bk1, t2);
    conv_mfma_k<64, 64, 1, false, true ><<<512, 256, 0, stream>>>(t2,  wk2p, bk2, kbuf);

    attn_k<<<256, 256, 0, stream>>>(qbuf, kbuf, z, (float*)d_out);
}

// Round 4
// 159.655 us; speedup vs baseline: 6.7405x; 2.5322x over previous
//
#include <hip/hip_runtime.h>
#include <hip/hip_bf16.h>

typedef _Float16 f16x8 __attribute__((ext_vector_type(8)));
typedef _Float16 f16x4 __attribute__((ext_vector_type(4)));
typedef float    f32x4 __attribute__((ext_vector_type(4)));

// ---- PE table: pe[p*128 + 2i] = sin(p*div_i), [..+1] = cos ---------------
__global__ void pe_fill_k(float* __restrict__ pe)
{
    int idx = blockIdx.x * 256 + threadIdx.x;   // 4096*64 (p, i) pairs
    int p = idx >> 6;
    int i = idx & 63;
    float div = expf(-0.07195578415606394f * (float)(2 * i)); // -ln(1e4)/128
    float arg = (float)p * div;
    pe[(p << 7) + 2 * i]     = sinf(arg);
    pe[(p << 7) + 2 * i + 1] = cosf(arg);
}

// ---- PE add + NCHW f32 -> NHWC f16 transpose ------------------------------
// Reads pe at the same per-batch FLAT offset as x (raw-reshape semantics).
__global__ __launch_bounds__(256)
void pe_tr_k(const float* __restrict__ x, const float* __restrict__ pe,
             _Float16* __restrict__ out, int PIX)
{
    __shared__ _Float16 t[64 * 136];
    const int tilesPerB = PIX >> 6;
    const int b  = blockIdx.x / tilesPerB;
    const int p0 = (blockIdx.x % tilesPerB) << 6;
    const int tid = threadIdx.x;
    const int c  = tid & 127;
    const int ph = (tid >> 7) << 5;              // 0 or 32

    const float* xr = x  + ((size_t)b * 128 + c) * PIX + p0 + ph;
    const float* pr = pe + (size_t)c * PIX + p0 + ph;
#pragma unroll
    for (int i = 0; i < 32; i += 4) {
        float4 xv = *(const float4*)(xr + i);
        float4 pv = *(const float4*)(pr + i);
        t[(ph + i + 0) * 136 + c] = (_Float16)(xv.x + pv.x);
        t[(ph + i + 1) * 136 + c] = (_Float16)(xv.y + pv.y);
        t[(ph + i + 2) * 136 + c] = (_Float16)(xv.z + pv.z);
        t[(ph + i + 3) * 136 + c] = (_Float16)(xv.w + pv.w);
    }
    __syncthreads();

    const int p  = tid >> 2;
    const int c0 = (tid & 3) << 5;
    _Float16* orow = out + ((size_t)b * PIX + p0 + p) * 128 + c0;
    uint4 v0 = *(const uint4*)&t[p * 136 + c0];
    uint4 v1 = *(const uint4*)&t[p * 136 + c0 + 8];
    uint4 v2 = *(const uint4*)&t[p * 136 + c0 + 16];
    uint4 v3 = *(const uint4*)&t[p * 136 + c0 + 24];
    ((uint4*)orow)[0] = v0; ((uint4*)orow)[1] = v1;
    ((uint4*)orow)[2] = v2; ((uint4*)orow)[3] = v3;
}

// ---- weight pack: OIHW f32 -> MFMA A-fragment-major f16 -------------------
__global__ void pack_w_k(const float* __restrict__ w, _Float16* __restrict__ out)
{
    int gid = blockIdx.x * 256 + threadIdx.x;    // 9*4*8*64 = 18432
    int f = gid >> 6, l = gid & 63;
    int t = f >> 5, cc = (f >> 3) & 3, m = f & 7;
    int co  = m * 16 + (l & 15);
    int ci0 = cc * 32 + (l >> 4) * 8;
    f16x8 pk;
#pragma unroll
    for (int i = 0; i < 8; ++i)
        pk[i] = (_Float16)w[(co * 128 + ci0 + i) * 9 + t];
    *(f16x8*)(out + (size_t)gid * 8) = pk;
}

// ---- implicit-GEMM 3x3 conv, MFMA 16x16x32 f16 ----------------------------
// In: NHWC f16. Out: NHWC f16 +ReLU, or NCHW f16 * oscale (for q/k).
template<int WW, int HH, int NROWS, bool RELU, bool NCHW_OUT>
__global__ __launch_bounds__(256)
void conv_mfma_k(const _Float16* __restrict__ in, const _Float16* __restrict__ wp,
                 const float* __restrict__ bias, void* __restrict__ outv,
                 float oscale)
{
    constexpr int PIX   = WW * HH;
    constexpr int SLABS = NROWS + 2;
    constexpr int NTPR  = WW / 16;               // n-tiles per image row
    constexpr int LST   = 136;                   // LDS row stride (f16 elems)

    __shared__ _Float16 lds[SLABS * WW * LST];

    const int bx  = blockIdx.x;
    const int b   = bx / (HH / NROWS);
    const int h0  = (bx % (HH / NROWS)) * NROWS;
    const int tid = threadIdx.x;
    const int wid = tid >> 6, lane = tid & 63;
    const int l15 = lane & 15, lg = lane >> 4;

    const _Float16* inb = in + (size_t)b * PIX * 128;
    constexpr int CHUNKS = SLABS * WW * 16;      // 16B chunks
    for (int cid = tid; cid < CHUNKS; cid += 256) {
        int s   = cid / (WW * 16);
        int rem = cid - s * (WW * 16);
        int w   = rem >> 4;
        int c8  = (rem & 15) * 8;
        int row = h0 - 1 + s;
        uint4 v = {0u, 0u, 0u, 0u};
        if (row >= 0 && row < HH)
            v = *(const uint4*)(inb + ((size_t)row * WW + w) * 128 + c8);
        *(uint4*)&lds[(s * WW + w) * LST + c8] = v;
    }
    __syncthreads();

    const int mbase = (wid >> 1) * 4;            // 4 m-tiles
    const int nbase = (wid & 1) * 2;             // 2 n-tiles

    f32x4 acc[4][2] = {};

    for (int cc = 0; cc < 4; ++cc) {
#pragma unroll
        for (int t = 0; t < 9; ++t) {
            const int dh = t / 3, dw = t % 3;
            f16x8 af[4];
#pragma unroll
            for (int mt = 0; mt < 4; ++mt) {
                int f = (t * 4 + cc) * 8 + (mbase + mt);
                af[mt] = *(const f16x8*)(wp + ((size_t)f * 64 + lane) * 8);
            }
            f16x8 bfr[2];
#pragma unroll
            for (int nt = 0; nt < 2; ++nt) {
                int ntile = nbase + nt;
                int nrow  = ntile / NTPR;
                int wbase = (ntile % NTPR) * 16;
                int slab  = nrow + dh;
                int wpix  = wbase + l15 + dw - 1;
                bool ok   = (unsigned)wpix < (unsigned)WW;
                int  wc   = ok ? wpix : 0;
                uint4 r = *(const uint4*)&lds[(slab * WW + wc) * LST + cc * 32 + lg * 8];
                if (!ok) r = uint4{0u, 0u, 0u, 0u};
                bfr[nt] = __builtin_bit_cast(f16x8, r);
            }
#pragma unroll
            for (int mt = 0; mt < 4; ++mt)
#pragma unroll
                for (int nt = 0; nt < 2; ++nt)
                    acc[mt][nt] = __builtin_amdgcn_mfma_f32_16x16x32_f16(
                        af[mt], bfr[nt], acc[mt][nt], 0, 0, 0);
        }
    }

#pragma unroll
    for (int mt = 0; mt < 4; ++mt) {
        int co = (mbase + mt) * 16 + lg * 4;
        float b0 = bias[co], b1 = bias[co + 1], b2 = bias[co + 2], b3 = bias[co + 3];
#pragma unroll
        for (int nt = 0; nt < 2; ++nt) {
            int ntile = nbase + nt;
            int nrow  = ntile / NTPR;
            int wbase = (ntile % NTPR) * 16;
            int p     = (h0 + nrow) * WW + wbase + l15;
            float v0 = acc[mt][nt][0] + b0;
            float v1 = acc[mt][nt][1] + b1;
            float v2 = acc[mt][nt][2] + b2;
            float v3 = acc[mt][nt][3] + b3;
            if (RELU) {
                v0 = fmaxf(v0, 0.f); v1 = fmaxf(v1, 0.f);
                v2 = fmaxf(v2, 0.f); v3 = fmaxf(v3, 0.f);
            }
            if (NCHW_OUT) {
                _Float16* ob = (_Float16*)outv + ((size_t)(b * 128 + co)) * PIX + p;
                ob[0]             = (_Float16)(v0 * oscale);
                ob[(size_t)PIX]   = (_Float16)(v1 * oscale);
                ob[(size_t)2*PIX] = (_Float16)(v2 * oscale);
                ob[(size_t)3*PIX] = (_Float16)(v3 * oscale);
            } else {
                _Float16* ob = (_Float16*)outv + ((size_t)b * PIX + p) * 128 + co;
                f16x4 pk = {(_Float16)v0, (_Float16)v1, (_Float16)v2, (_Float16)v3};
                *(f16x4*)ob = pk;
            }
        }
    }
}

// ---- MFMA flash attention -------------------------------------------------
// Block = (b, 32 q-rows), 8 waves; wave w owns keys [w*512, w*512+512).
// mfma(A=K_tile, B=Q): lane's acc = 4 keys x 1 q-row -> per-lane online
// softmax (keys register-local), merge via shfl_xor(16,32) + LDS over waves.
// q is pre-scaled by 128^-0.5 in the conv epilogue.
__global__ __launch_bounds__(512)
void attn_mfma_k(const _Float16* __restrict__ q, const _Float16* __restrict__ k,
                 const float* __restrict__ v, float* __restrict__ out)
{
    __shared__ float vs[4096];
    __shared__ float red[8][32][4];

    const int bx  = blockIdx.x;
    const int b   = bx & 7;                      // XCD-local batch
    const int qt  = bx >> 3;
    const int tid = threadIdx.x;
    const int wid = tid >> 6, lane = tid & 63;
    const int l15 = lane & 15, lg = lane >> 4;

    const _Float16* qb = q + ((size_t)b * 1024 + qt * 32) * 128;
    const _Float16* kb = k + ((size_t)b * 4096 + wid * 512) * 128;
    const float*    vb = v + (size_t)b * 4096;

    for (int t = tid; t < 1024; t += 512)
        *(float4*)&vs[t * 4] = *(const float4*)&vb[t * 4];

    f16x8 qf[2][4];
#pragma unroll
    for (int qti = 0; qti < 2; ++qti)
#pragma unroll
        for (int cc = 0; cc < 4; ++cc)
            qf[qti][cc] = *(const f16x8*)(qb + (size_t)(qti * 16 + l15) * 128 + cc * 32 + lg * 8);
    __syncthreads();

    float m[2]   = {-1e30f, -1e30f};
    float num[2] = {0.f, 0.f};
    float den[2] = {0.f, 0.f};

    f16x8 kf[4];
#pragma unroll
    for (int cc = 0; cc < 4; ++cc)
        kf[cc] = *(const f16x8*)(kb + (size_t)l15 * 128 + cc * 32 + lg * 8);

    for (int kt = 0; kt < 32; ++kt) {
        f16x8 kn[4];
        if (kt + 1 < 32) {
#pragma unroll
            for (int cc = 0; cc < 4; ++cc)
                kn[cc] = *(const f16x8*)(kb + (size_t)((kt + 1) * 16 + l15) * 128 + cc * 32 + lg * 8);
        }

        f32x4 acc[2] = {};
#pragma unroll
        for (int cc = 0; cc < 4; ++cc) {
            acc[0] = __builtin_amdgcn_mfma_f32_16x16x32_f16(kf[cc], qf[0][cc], acc[0], 0, 0, 0);
            acc[1] = __builtin_amdgcn_mfma_f32_16x16x32_f16(kf[cc], qf[1][cc], acc[1], 0, 0, 0);
        }

        float4 vv = *(const float4*)&vs[wid * 512 + kt * 16 + lg * 4];
#pragma unroll
        for (int qti = 0; qti < 2; ++qti) {
            float s0 = acc[qti][0], s1 = acc[qti][1], s2 = acc[qti][2], s3 = acc[qti][3];
            float smax = fmaxf(fmaxf(s0, s1), fmaxf(s2, s3));
            float mn = fmaxf(m[qti], smax);
            float c0 = __expf(m[qti] - mn);
            float e0 = __expf(s0 - mn);
            float e1 = __expf(s1 - mn);
            float e2 = __expf(s2 - mn);
            float e3 = __expf(s3 - mn);
            num[qti] = num[qti] * c0 + e0 * vv.x + e1 * vv.y + e2 * vv.z + e3 * vv.w;
            den[qti] = den[qti] * c0 + ((e0 + e1) + (e2 + e3));
            m[qti]   = mn;
        }

        if (kt + 1 < 32) {
#pragma unroll
            for (int cc = 0; cc < 4; ++cc) kf[cc] = kn[cc];
        }
    }

    // merge the 4 lane-groups (same l15 = same q-row)
#pragma unroll
    for (int off = 16; off <= 32; off <<= 1) {
#pragma unroll
        for (int qti = 0; qti < 2; ++qti) {
            float mo = __shfl_xor(m[qti], off);
            float no = __shfl_xor(num[qti], off);
            float dd = __shfl_xor(den[qti], off);
            float mn = fmaxf(m[qti], mo);
            float c0 = __expf(m[qti] - mn);
            float c1 = __expf(mo - mn);
            num[qti] = num[qti] * c0 + no * c1;
            den[qti] = den[qti] * c0 + dd * c1;
            m[qti]   = mn;
        }
    }
    if (lg == 0) {
#pragma unroll
        for (int qti = 0; qti < 2; ++qti) {
            red[wid][qti * 16 + l15][0] = m[qti];
            red[wid][qti * 16 + l15][1] = num[qti];
            red[wid][qti * 16 + l15][2] = den[qti];
        }
    }
    __syncthreads();
    if (tid < 32) {
        float M = -1e30f, N = 0.f, D = 0.f;
#pragma unroll
        for (int w = 0; w < 8; ++w) {
            float mo = red[w][tid][0], no = red[w][tid][1], dd = red[w][tid][2];
            float mn = fmaxf(M, mo);
            float c0 = __expf(M - mn);
            float c1 = __expf(mo - mn);
            N = N * c0 + no * c1;
            D = D * c0 + dd * c1;
            M = mn;
        }
        out[(size_t)b * 1024 + qt * 32 + tid] = N / D;
    }
}

// ---------------------------------------------------------------------------
extern "C" void kernel_launch(void* const* d_in, const int* in_sizes, int n_in,
                              void* d_out, int out_size, void* d_ws, size_t ws_size,
                              hipStream_t stream)
{
    const float* x   = (const float*)d_in[0];   // 8*128*32*32
    const float* y   = (const float*)d_in[1];   // 8*128*64*64
    const float* z   = (const float*)d_in[2];   // 8*1*64*64
    const float* wq1 = (const float*)d_in[3];
    const float* bq1 = (const float*)d_in[4];
    const float* wq2 = (const float*)d_in[5];
    const float* bq2 = (const float*)d_in[6];
    const float* wk1 = (const float*)d_in[7];
    const float* bk1 = (const float*)d_in[8];
    const float* wk2 = (const float*)d_in[9];
    const float* bk2 = (const float*)d_in[10];

    char* w8 = (char*)d_ws;
    float*    pe   = (float*)(w8);                     // 2 MB
    _Float16* xpe  = (_Float16*)(w8 + (2u  << 20));    // 2 MB  NHWC f16
    _Float16* ype  = (_Float16*)(w8 + (4u  << 20));    // 8 MB  NHWC f16
    _Float16* t1   = (_Float16*)(w8 + (12u << 20));    // 2 MB  NHWC f16
    _Float16* t2   = (_Float16*)(w8 + (14u << 20));    // 8 MB  NHWC f16
    _Float16* qbuf = (_Float16*)(w8 + (22u << 20));    // 2 MB  NCHW f16 (scaled)
    _Float16* kbuf = (_Float16*)(w8 + (24u << 20));    // 8 MB  NCHW f16
    _Float16* wq1p = (_Float16*)(w8 + (32u << 20));    // 288 KB each
    _Float16* wq2p = wq1p + 147456;
    _Float16* wk1p = wq2p + 147456;
    _Float16* wk2p = wk1p + 147456;

    const float scale = 0.08838834764831845f;          // 128^-0.5

    pe_fill_k<<<1024, 256, 0, stream>>>(pe);
    pe_tr_k<<<128, 256, 0, stream>>>(x, pe, xpe, 1024);
    pe_tr_k<<<512, 256, 0, stream>>>(y, pe, ype, 4096);

    pack_w_k<<<72, 256, 0, stream>>>(wq1, wq1p);
    pack_w_k<<<72, 256, 0, stream>>>(wq2, wq2p);
    pack_w_k<<<72, 256, 0, stream>>>(wk1, wk1p);
    pack_w_k<<<72, 256, 0, stream>>>(wk2, wk2p);

    conv_mfma_k<32, 32, 2, true,  false><<<128, 256, 0, stream>>>(xpe, wq1p, bq1, t1,   1.f);
    conv_mfma_k<32, 32, 2, false, true ><<<128, 256, 0, stream>>>(t1,  wq2p, bq2, qbuf, scale);
    conv_mfma_k<64, 64, 1, true,  false><<<512, 256, 0, stream>>>(ype, wk1p, bk1, t2,   1.f);
    conv_mfma_k<64, 64, 1, false, true ><<<512, 256, 0, stream>>>(t2,  wk2p, bk2, kbuf, 1.f);

    attn_mfma_k<<<256, 512, 0, stream>>>(qbuf, kbuf, z, (float*)d_out);
}

// Round 5
// 121.088 us; speedup vs baseline: 8.8873x; 1.3185x over previous
//
#include <hip/hip_runtime.h>
#include <hip/hip_bf16.h>

typedef _Float16 f16x8 __attribute__((ext_vector_type(8)));
typedef _Float16 f16x4 __attribute__((ext_vector_type(4)));
typedef float    f32x4 __attribute__((ext_vector_type(4)));

#define PE_K (-0.07195578415606394f)   // -ln(10000)/128

// ---------------------------------------------------------------------------
// prep_k: fused {PE-add + NCHW f32 -> NHWC f16 transpose} for x and y, plus
// all 4 weight packs. blocks [0,128)=x tiles, [128,640)=y tiles, [640,928)=pack.
// PE is computed on the fly: for flat per-batch index f = c*PIX + p,
// col = f&127 = p&127 (PIX % 128 == 0), row = c*(PIX/128) + (p>>7); each
// thread's 32-pixel run never crosses a 128-boundary -> row is constant.
// ---------------------------------------------------------------------------
__global__ __launch_bounds__(256)
void prep_k(const float* __restrict__ x, const float* __restrict__ y,
            const float* __restrict__ wq1, const float* __restrict__ wq2,
            const float* __restrict__ wk1, const float* __restrict__ wk2,
            _Float16* __restrict__ xpe, _Float16* __restrict__ ype,
            _Float16* __restrict__ wp)
{
    __shared__ _Float16 sh[64 * 136];
    const int bx  = blockIdx.x;
    const int tid = threadIdx.x;

    if (bx < 640) {
        const float* src; _Float16* dst; int PIX, b, p0;
        if (bx < 128) { src = x; dst = xpe; PIX = 1024; b = bx >> 4; p0 = (bx & 15) << 6; }
        else { int t = bx - 128; src = y; dst = ype; PIX = 4096; b = t >> 6; p0 = (t & 63) << 6; }

        const int c     = tid & 127;
        const int ph    = (tid >> 7) << 5;           // 0 or 32
        const int start = p0 + ph;
        const float frow = (float)(c * (PIX >> 7) + (start >> 7));
        const int colbase = start & 127;

        const float* xr = src + ((size_t)b * 128 + c) * PIX + start;
#pragma unroll
        for (int i = 0; i < 32; i += 4) {
            float4 xv = *(const float4*)(xr + i);
            int col = colbase + i;                   // even
            float s0, c0, s1, c1;
            __sincosf(frow * __expf(PE_K * (float)col),       &s0, &c0);
            __sincosf(frow * __expf(PE_K * (float)(col + 2)), &s1, &c1);
            sh[(ph + i + 0) * 136 + c] = (_Float16)(xv.x + s0);
            sh[(ph + i + 1) * 136 + c] = (_Float16)(xv.y + c0);
            sh[(ph + i + 2) * 136 + c] = (_Float16)(xv.z + s1);
            sh[(ph + i + 3) * 136 + c] = (_Float16)(xv.w + c1);
        }
        __syncthreads();

        const int p   = tid >> 2;
        const int c0i = (tid & 3) << 5;
        _Float16* orow = dst + ((size_t)b * PIX + p0 + p) * 128 + c0i;
        uint4 v0 = *(const uint4*)&sh[p * 136 + c0i];
        uint4 v1 = *(const uint4*)&sh[p * 136 + c0i + 8];
        uint4 v2 = *(const uint4*)&sh[p * 136 + c0i + 16];
        uint4 v3 = *(const uint4*)&sh[p * 136 + c0i + 24];
        ((uint4*)orow)[0] = v0; ((uint4*)orow)[1] = v1;
        ((uint4*)orow)[2] = v2; ((uint4*)orow)[3] = v3;
    } else {
        // weight pack: OIHW f32 -> MFMA A-fragment-major f16
        int g    = bx - 640;                         // 0..287
        int widx = g / 72;                           // uniform per block
        const float* w = widx == 0 ? wq1 : widx == 1 ? wq2 : widx == 2 ? wk1 : wk2;
        _Float16*    o = wp + (size_t)widx * 147456;
        int gid = (g - widx * 72) * 256 + tid;       // 0..18431
        int f = gid >> 6, l = gid & 63;
        int t = f >> 5, cc = (f >> 3) & 3, mm = f & 7;
        int co  = mm * 16 + (l & 15);
        int ci0 = cc * 32 + (l >> 4) * 8;
        f16x8 pk;
#pragma unroll
        for (int i = 0; i < 8; ++i)
            pk[i] = (_Float16)w[(co * 128 + ci0 + i) * 9 + t];
        *(f16x8*)(o + (size_t)gid * 8) = pk;
    }
}

// ---------------------------------------------------------------------------
// implicit-GEMM 3x3 conv, MFMA 16x16x32 f16. In: NHWC f16.
// Out: NHWC f16 +ReLU, or NCHW f16 * oscale. COSPLIT splits the 128 co
// across blocks (2 -> 64 co per block) to double grid parallelism.
// ---------------------------------------------------------------------------
template<int WW, int HH, int NROWS, int COSPLIT, bool RELU, bool NCHW_OUT>
__global__ __launch_bounds__(256)
void conv_mfma_k(const _Float16* __restrict__ in, const _Float16* __restrict__ wp,
                 const float* __restrict__ bias, void* __restrict__ outv,
                 float oscale)
{
    constexpr int PIX   = WW * HH;
    constexpr int SLABS = NROWS + 2;
    constexpr int NTPR  = WW / 16;
    constexpr int LST   = 136;
    constexpr int GPB   = (HH / NROWS) * COSPLIT;
    constexpr int MTW   = 4 / COSPLIT;               // m-tiles per wave

    __shared__ _Float16 lds[SLABS * WW * LST];

    const int bx  = blockIdx.x;
    const int b   = bx / GPB;
    const int r   = bx % GPB;
    const int h0  = (r / COSPLIT) * NROWS;
    const int ch  = r % COSPLIT;
    const int tid = threadIdx.x;
    const int wid = tid >> 6, lane = tid & 63;
    const int l15 = lane & 15, lg = lane >> 4;

    const _Float16* inb = in + (size_t)b * PIX * 128;
    constexpr int CHUNKS = SLABS * WW * 16;
    for (int cid = tid; cid < CHUNKS; cid += 256) {
        int s   = cid / (WW * 16);
        int rem = cid - s * (WW * 16);
        int w   = rem >> 4;
        int c8  = (rem & 15) * 8;
        int row = h0 - 1 + s;
        uint4 v = {0u, 0u, 0u, 0u};
        if (row >= 0 && row < HH)
            v = *(const uint4*)(inb + ((size_t)row * WW + w) * 128 + c8);
        *(uint4*)&lds[(s * WW + w) * LST + c8] = v;
    }
    __syncthreads();

    const int mbase = ch * (8 / COSPLIT) + (wid >> 1) * MTW;
    const int nbase = (wid & 1) * 2;

    f32x4 acc[MTW][2] = {};

    for (int cc = 0; cc < 4; ++cc) {
#pragma unroll
        for (int t = 0; t < 9; ++t) {
            const int dh = t / 3, dw = t % 3;
            f16x8 af[MTW];
#pragma unroll
            for (int mt = 0; mt < MTW; ++mt) {
                int f = (t * 4 + cc) * 8 + (mbase + mt);
                af[mt] = *(const f16x8*)(wp + ((size_t)f * 64 + lane) * 8);
            }
            f16x8 bfr[2];
#pragma unroll
            for (int nt = 0; nt < 2; ++nt) {
                int ntile = nbase + nt;
                int nrow  = ntile / NTPR;
                int wbase = (ntile % NTPR) * 16;
                int slab  = nrow + dh;
                int wpix  = wbase + l15 + dw - 1;
                bool ok   = (unsigned)wpix < (unsigned)WW;
                int  wc   = ok ? wpix : 0;
                uint4 rr = *(const uint4*)&lds[(slab * WW + wc) * LST + cc * 32 + lg * 8];
                if (!ok) rr = uint4{0u, 0u, 0u, 0u};
                bfr[nt] = __builtin_bit_cast(f16x8, rr);
            }
#pragma unroll
            for (int mt = 0; mt < MTW; ++mt)
#pragma unroll
                for (int nt = 0; nt < 2; ++nt)
                    acc[mt][nt] = __builtin_amdgcn_mfma_f32_16x16x32_f16(
                        af[mt], bfr[nt], acc[mt][nt], 0, 0, 0);
        }
    }

#pragma unroll
    for (int mt = 0; mt < MTW; ++mt) {
        int co = (mbase + mt) * 16 + lg * 4;
        float b0 = bias[co], b1 = bias[co + 1], b2 = bias[co + 2], b3 = bias[co + 3];
#pragma unroll
        for (int nt = 0; nt < 2; ++nt) {
            int ntile = nbase + nt;
            int nrow  = ntile / NTPR;
            int wbase = (ntile % NTPR) * 16;
            int p     = (h0 + nrow) * WW + wbase + l15;
            float v0 = acc[mt][nt][0] + b0;
            float v1 = acc[mt][nt][1] + b1;
            float v2 = acc[mt][nt][2] + b2;
            float v3 = acc[mt][nt][3] + b3;
            if (RELU) {
                v0 = fmaxf(v0, 0.f); v1 = fmaxf(v1, 0.f);
                v2 = fmaxf(v2, 0.f); v3 = fmaxf(v3, 0.f);
            }
            if (NCHW_OUT) {
                _Float16* ob = (_Float16*)outv + ((size_t)(b * 128 + co)) * PIX + p;
                ob[0]             = (_Float16)(v0 * oscale);
                ob[(size_t)PIX]   = (_Float16)(v1 * oscale);
                ob[(size_t)2*PIX] = (_Float16)(v2 * oscale);
                ob[(size_t)3*PIX] = (_Float16)(v3 * oscale);
            } else {
                _Float16* ob = (_Float16*)outv + ((size_t)b * PIX + p) * 128 + co;
                f16x4 pk = {(_Float16)v0, (_Float16)v1, (_Float16)v2, (_Float16)v3};
                *(f16x4*)ob = pk;
            }
        }
    }
}

// ---------------------------------------------------------------------------
// MFMA flash attention, split-K 2-way. Block = (b, 64 q-rows, kv half).
// 8 waves; wave owns 256 keys (16 tiles of 16). mfma(A=K, B=Q): lane's acc =
// 4 keys x 1 q-row; per-lane online softmax; shfl merge over lg; LDS merge
// over waves; partials (m,num,den) to ws; attn_fin_k combines the 2 halves.
// q pre-scaled by 128^-0.5 in the conv epilogue.
// ---------------------------------------------------------------------------
__global__ __launch_bounds__(512)
void attn_mfma_k(const _Float16* __restrict__ q, const _Float16* __restrict__ k,
                 const float* __restrict__ v, float* __restrict__ part)
{
    __shared__ float vs[2048];
    __shared__ float red[8][64][3];

    const int bx  = blockIdx.x;
    const int b   = bx & 7;                          // XCD-pinned batch
    const int qt  = (bx >> 3) & 15;
    const int kv  = bx >> 7;
    const int tid = threadIdx.x;
    const int wid = tid >> 6, lane = tid & 63;
    const int l15 = lane & 15, lg = lane >> 4;

    const _Float16* qb = q + ((size_t)b * 1024 + qt * 64) * 128;
    const _Float16* kb = k + ((size_t)b * 4096 + kv * 2048 + wid * 256) * 128;
    const float*    vb = v + (size_t)b * 4096 + kv * 2048;

    *(float4*)&vs[tid * 4] = *(const float4*)&vb[tid * 4];

    f16x8 qf[4][4];
#pragma unroll
    for (int qti = 0; qti < 4; ++qti)
#pragma unroll
        for (int cc = 0; cc < 4; ++cc)
            qf[qti][cc] = *(const f16x8*)(qb + (size_t)(qti * 16 + l15) * 128 + cc * 32 + lg * 8);
    __syncthreads();

    float m[4], num[4], den[4];
#pragma unroll
    for (int a = 0; a < 4; ++a) { m[a] = -1e30f; num[a] = 0.f; den[a] = 0.f; }

    f16x8 kf[2][4];
#pragma unroll
    for (int cc = 0; cc < 4; ++cc) {
        kf[0][cc] = *(const f16x8*)(kb + (size_t)(l15)      * 128 + cc * 32 + lg * 8);
        kf[1][cc] = *(const f16x8*)(kb + (size_t)(16 + l15) * 128 + cc * 32 + lg * 8);
    }

#pragma unroll
    for (int kt = 0; kt < 16; ++kt) {
        f32x4 acc[4] = {};
#pragma unroll
        for (int cc = 0; cc < 4; ++cc) {
#pragma unroll
            for (int qti = 0; qti < 4; ++qti)
                acc[qti] = __builtin_amdgcn_mfma_f32_16x16x32_f16(
                    kf[kt & 1][cc], qf[qti][cc], acc[qti], 0, 0, 0);
        }
        if (kt + 2 < 16) {
#pragma unroll
            for (int cc = 0; cc < 4; ++cc)
                kf[kt & 1][cc] = *(const f16x8*)(kb + (size_t)((kt + 2) * 16 + l15) * 128 + cc * 32 + lg * 8);
        }

        float4 vv = *(const float4*)&vs[wid * 256 + kt * 16 + lg * 4];
#pragma unroll
        for (int qti = 0; qti < 4; ++qti) {
            float s0 = acc[qti][0], s1 = acc[qti][1], s2 = acc[qti][2], s3 = acc[qti][3];
            float smax = fmaxf(fmaxf(s0, s1), fmaxf(s2, s3));
            float mn = fmaxf(m[qti], smax);
            float c0 = __expf(m[qti] - mn);
            float e0 = __expf(s0 - mn);
            float e1 = __expf(s1 - mn);
            float e2 = __expf(s2 - mn);
            float e3 = __expf(s3 - mn);
            num[qti] = num[qti] * c0 + e0 * vv.x + e1 * vv.y + e2 * vv.z + e3 * vv.w;
            den[qti] = den[qti] * c0 + ((e0 + e1) + (e2 + e3));
            m[qti]   = mn;
        }
    }

#pragma unroll
    for (int off = 16; off <= 32; off <<= 1) {
#pragma unroll
        for (int qti = 0; qti < 4; ++qti) {
            float mo = __shfl_xor(m[qti], off);
            float no = __shfl_xor(num[qti], off);
            float dd = __shfl_xor(den[qti], off);
            float mn = fmaxf(m[qti], mo);
            float c0 = __expf(m[qti] - mn);
            float c1 = __expf(mo - mn);
            num[qti] = num[qti] * c0 + no * c1;
            den[qti] = den[qti] * c0 + dd * c1;
            m[qti]   = mn;
        }
    }
    if (lg == 0) {
#pragma unroll
        for (int qti = 0; qti < 4; ++qti) {
            red[wid][qti * 16 + l15][0] = m[qti];
            red[wid][qti * 16 + l15][1] = num[qti];
            red[wid][qti * 16 + l15][2] = den[qti];
        }
    }
    __syncthreads();
    if (tid < 64) {
        float M = -1e30f, N = 0.f, D = 0.f;
#pragma unroll
        for (int w = 0; w < 8; ++w) {
            float mo = red[w][tid][0], no = red[w][tid][1], dd = red[w][tid][2];
            float mn = fmaxf(M, mo);
            float c0 = __expf(M - mn);
            float c1 = __expf(mo - mn);
            N = N * c0 + no * c1;
            D = D * c0 + dd * c1;
            M = mn;
        }
        float4 o = {M, N, D, 0.f};
        ((float4*)part)[((size_t)(b * 2 + kv)) * 1024 + qt * 64 + tid] = o;
    }
}

// ---- combine the 2 kv-half partials per q-row -----------------------------
__global__ __launch_bounds__(256)
void attn_fin_k(const float* __restrict__ part, float* __restrict__ out)
{
    int gid = blockIdx.x * 256 + threadIdx.x;        // 8192
    int b = gid >> 10, row = gid & 1023;
    const float4* p4 = (const float4*)part;
    float4 a = p4[(size_t)(b * 2 + 0) * 1024 + row];
    float4 c = p4[(size_t)(b * 2 + 1) * 1024 + row];
    float mn = fmaxf(a.x, c.x);
    float ea = __expf(a.x - mn), ec = __expf(c.x - mn);
    out[gid] = (a.y * ea + c.y * ec) / (a.z * ea + c.z * ec);
}

// ---------------------------------------------------------------------------
extern "C" void kernel_launch(void* const* d_in, const int* in_sizes, int n_in,
                              void* d_out, int out_size, void* d_ws, size_t ws_size,
                              hipStream_t stream)
{
    const float* x   = (const float*)d_in[0];
    const float* y   = (const float*)d_in[1];
    const float* z   = (const float*)d_in[2];
    const float* wq1 = (const float*)d_in[3];
    const float* bq1 = (const float*)d_in[4];
    const float* wq2 = (const float*)d_in[5];
    const float* bq2 = (const float*)d_in[6];
    const float* wk1 = (const float*)d_in[7];
    const float* bk1 = (const float*)d_in[8];
    const float* wk2 = (const float*)d_in[9];
    const float* bk2 = (const float*)d_in[10];

    char* w8 = (char*)d_ws;
    _Float16* xpe  = (_Float16*)(w8);                  // 2 MB  NHWC f16
    _Float16* ype  = (_Float16*)(w8 + (2u  << 20));    // 8 MB  NHWC f16
    _Float16* t1   = (_Float16*)(w8 + (10u << 20));    // 2 MB  NHWC f16
    _Float16* t2   = (_Float16*)(w8 + (12u << 20));    // 8 MB  NHWC f16
    _Float16* qbuf = (_Float16*)(w8 + (20u << 20));    // 2 MB  NCHW f16 (scaled)
    _Float16* kbuf = (_Float16*)(w8 + (22u << 20));    // 8 MB  NCHW f16
    _Float16* wp   = (_Float16*)(w8 + (30u << 20));    // 4 x 288 KB packs
    float*    part = (float*)   (w8 + (32u << 20));    // 256 KB partials

    const float scale = 0.08838834764831845f;          // 128^-0.5

    prep_k<<<928, 256, 0, stream>>>(x, y, wq1, wq2, wk1, wk2, xpe, ype, wp);

    conv_mfma_k<32, 32, 2, 2, true,  false><<<256, 256, 0, stream>>>(xpe, wp,              bq1, t1,   1.f);
    conv_mfma_k<32, 32, 2, 2, false, true ><<<256, 256, 0, stream>>>(t1,  wp + 147456,     bq2, qbuf, scale);
    conv_mfma_k<64, 64, 1, 1, true,  false><<<512, 256, 0, stream>>>(ype, wp + 2 * 147456, bk1, t2,   1.f);
    conv_mfma_k<64, 64, 1, 1, false, true ><<<512, 256, 0, stream>>>(t2,  wp + 3 * 147456, bk2, kbuf, 1.f);

    attn_mfma_k<<<256, 512, 0, stream>>>(qbuf, kbuf, z, part);
    attn_fin_k<<<32, 256, 0, stream>>>(part, (float*)d_out);
}

// Round 6
// 118.504 us; speedup vs baseline: 9.0811x; 1.0218x over previous
//
#include <hip/hip_runtime.h>
#include <hip/hip_bf16.h>

typedef _Float16 f16x8 __attribute__((ext_vector_type(8)));
typedef _Float16 f16x4 __attribute__((ext_vector_type(4)));
typedef float    f32x4 __attribute__((ext_vector_type(4)));

#define PE_K (-0.07195578415606394f)   // -ln(10000)/128

// ---------------------------------------------------------------------------
// prep_k: fused {PE-add + NCHW f32 -> NHWC f16 transpose} for x and y, plus
// all 4 weight packs. blocks [0,128)=x tiles, [128,640)=y tiles, [640,928)=pack.
// PE on the fly: flat per-batch index f = c*PIX + p -> pe row = f/128 (const
// across each thread's 32-pixel run), col = f&127.
// ---------------------------------------------------------------------------
__global__ __launch_bounds__(256)
void prep_k(const float* __restrict__ x, const float* __restrict__ y,
            const float* __restrict__ wq1, const float* __restrict__ wq2,
            const float* __restrict__ wk1, const float* __restrict__ wk2,
            _Float16* __restrict__ xpe, _Float16* __restrict__ ype,
            _Float16* __restrict__ wp)
{
    __shared__ _Float16 sh[64 * 136];
    const int bx  = blockIdx.x;
    const int tid = threadIdx.x;

    if (bx < 640) {
        const float* src; _Float16* dst; int PIX, b, p0;
        if (bx < 128) { src = x; dst = xpe; PIX = 1024; b = bx >> 4; p0 = (bx & 15) << 6; }
        else { int t = bx - 128; src = y; dst = ype; PIX = 4096; b = t >> 6; p0 = (t & 63) << 6; }

        const int c     = tid & 127;
        const int ph    = (tid >> 7) << 5;           // 0 or 32
        const int start = p0 + ph;
        const float frow = (float)(c * (PIX >> 7) + (start >> 7));
        const int colbase = start & 127;

        const float* xr = src + ((size_t)b * 128 + c) * PIX + start;
#pragma unroll
        for (int i = 0; i < 32; i += 4) {
            float4 xv = *(const float4*)(xr + i);
            int col = colbase + i;                   // even
            float s0, c0, s1, c1;
            __sincosf(frow * __expf(PE_K * (float)col),       &s0, &c0);
            __sincosf(frow * __expf(PE_K * (float)(col + 2)), &s1, &c1);
            sh[(ph + i + 0) * 136 + c] = (_Float16)(xv.x + s0);
            sh[(ph + i + 1) * 136 + c] = (_Float16)(xv.y + c0);
            sh[(ph + i + 2) * 136 + c] = (_Float16)(xv.z + s1);
            sh[(ph + i + 3) * 136 + c] = (_Float16)(xv.w + c1);
        }
        __syncthreads();

        const int p   = tid >> 2;
        const int c0i = (tid & 3) << 5;
        _Float16* orow = dst + ((size_t)b * PIX + p0 + p) * 128 + c0i;
        uint4 v0 = *(const uint4*)&sh[p * 136 + c0i];
        uint4 v1 = *(const uint4*)&sh[p * 136 + c0i + 8];
        uint4 v2 = *(const uint4*)&sh[p * 136 + c0i + 16];
        uint4 v3 = *(const uint4*)&sh[p * 136 + c0i + 24];
        ((uint4*)orow)[0] = v0; ((uint4*)orow)[1] = v1;
        ((uint4*)orow)[2] = v2; ((uint4*)orow)[3] = v3;
    } else {
        // weight pack: OIHW f32 -> MFMA A-fragment-major f16
        int g    = bx - 640;                         // 0..287
        int widx = g / 72;                           // uniform per block
        const float* w = widx == 0 ? wq1 : widx == 1 ? wq2 : widx == 2 ? wk1 : wk2;
        _Float16*    o = wp + (size_t)widx * 147456;
        int gid = (g - widx * 72) * 256 + tid;       // 0..18431
        int f = gid >> 6, l = gid & 63;
        int t = f >> 5, cc = (f >> 3) & 3, mm = f & 7;
        int co  = mm * 16 + (l & 15);
        int ci0 = cc * 32 + (l >> 4) * 8;
        f16x8 pk;
#pragma unroll
        for (int i = 0; i < 8; ++i)
            pk[i] = (_Float16)w[(co * 128 + ci0 + i) * 9 + t];
        *(f16x8*)(o + (size_t)gid * 8) = pk;
    }
}

// ---------------------------------------------------------------------------
// implicit-GEMM 3x3 conv body, MFMA 16x16x32 f16. In: NHWC f16.
// Out: NHWC f16 +ReLU, or NCHW f16 * oscale. Wave = MTW m-tiles x NTW n-tiles.
// ---------------------------------------------------------------------------
template<int WW, int HH, int NROWS, int COSPLIT, int MTW, int NTW,
         bool RELU, bool NCHW_OUT>
__device__ __forceinline__
void conv_body(const _Float16* __restrict__ in, const _Float16* __restrict__ wp,
               const float* __restrict__ bias, void* __restrict__ outv,
               float oscale, int bx, _Float16* lds)
{
    constexpr int PIX   = WW * HH;
    constexpr int SLABS = NROWS + 2;
    constexpr int NTPR  = WW / 16;
    constexpr int LST   = 136;
    constexpr int GPB   = (HH / NROWS) * COSPLIT;
    constexpr int NGRP  = (NROWS * NTPR) / NTW;      // n-groups (waves)
    static_assert(((8 / COSPLIT) / MTW) * NGRP == 4, "wave mapping");

    const int b   = bx / GPB;
    const int r   = bx % GPB;
    const int h0  = (r / COSPLIT) * NROWS;
    const int ch  = r % COSPLIT;
    const int tid = threadIdx.x;
    const int wid = tid >> 6, lane = tid & 63;
    const int l15 = lane & 15, lg = lane >> 4;

    const _Float16* inb = in + (size_t)b * PIX * 128;
    constexpr int CHUNKS = SLABS * WW * 16;
    for (int cid = tid; cid < CHUNKS; cid += 256) {
        int s   = cid / (WW * 16);
        int rem = cid - s * (WW * 16);
        int w   = rem >> 4;
        int c8  = (rem & 15) * 8;
        int row = h0 - 1 + s;
        uint4 v = {0u, 0u, 0u, 0u};
        if (row >= 0 && row < HH)
            v = *(const uint4*)(inb + ((size_t)row * WW + w) * 128 + c8);
        *(uint4*)&lds[(s * WW + w) * LST + c8] = v;
    }
    __syncthreads();

    const int mbase = ch * (8 / COSPLIT) + (wid / NGRP) * MTW;
    const int nbase = (wid % NGRP) * NTW;

    f32x4 acc[MTW][NTW] = {};

    for (int cc = 0; cc < 4; ++cc) {
#pragma unroll
        for (int t = 0; t < 9; ++t) {
            const int dh = t / 3, dw = t % 3;
            f16x8 af[MTW];
#pragma unroll
            for (int mt = 0; mt < MTW; ++mt) {
                int f = (t * 4 + cc) * 8 + (mbase + mt);
                af[mt] = *(const f16x8*)(wp + ((size_t)f * 64 + lane) * 8);
            }
            f16x8 bfr[NTW];
#pragma unroll
            for (int nt = 0; nt < NTW; ++nt) {
                int ntile = nbase + nt;
                int nrow  = ntile / NTPR;
                int wbase = (ntile % NTPR) * 16;
                int slab  = nrow + dh;
                int wpix  = wbase + l15 + dw - 1;
                bool ok   = (unsigned)wpix < (unsigned)WW;
                int  wc   = ok ? wpix : 0;
                uint4 rr = *(const uint4*)&lds[(slab * WW + wc) * LST + cc * 32 + lg * 8];
                if (!ok) rr = uint4{0u, 0u, 0u, 0u};
                bfr[nt] = __builtin_bit_cast(f16x8, rr);
            }
#pragma unroll
            for (int mt = 0; mt < MTW; ++mt)
#pragma unroll
                for (int nt = 0; nt < NTW; ++nt)
                    acc[mt][nt] = __builtin_amdgcn_mfma_f32_16x16x32_f16(
                        af[mt], bfr[nt], acc[mt][nt], 0, 0, 0);
        }
    }

#pragma unroll
    for (int mt = 0; mt < MTW; ++mt) {
        int co = (mbase + mt) * 16 + lg * 4;
        float b0 = bias[co], b1 = bias[co + 1], b2 = bias[co + 2], b3 = bias[co + 3];
#pragma unroll
        for (int nt = 0; nt < NTW; ++nt) {
            int ntile = nbase + nt;
            int nrow  = ntile / NTPR;
            int wbase = (ntile % NTPR) * 16;
            int p     = (h0 + nrow) * WW + wbase + l15;
            float v0 = acc[mt][nt][0] + b0;
            float v1 = acc[mt][nt][1] + b1;
            float v2 = acc[mt][nt][2] + b2;
            float v3 = acc[mt][nt][3] + b3;
            if (RELU) {
                v0 = fmaxf(v0, 0.f); v1 = fmaxf(v1, 0.f);
                v2 = fmaxf(v2, 0.f); v3 = fmaxf(v3, 0.f);
            }
            if (NCHW_OUT) {
                _Float16* ob = (_Float16*)outv + ((size_t)(b * 128 + co)) * PIX + p;
                ob[0]             = (_Float16)(v0 * oscale);
                ob[(size_t)PIX]   = (_Float16)(v1 * oscale);
                ob[(size_t)2*PIX] = (_Float16)(v2 * oscale);
                ob[(size_t)3*PIX] = (_Float16)(v3 * oscale);
            } else {
                _Float16* ob = (_Float16*)outv + ((size_t)b * PIX + p) * 128 + co;
                f16x4 pk = {(_Float16)v0, (_Float16)v1, (_Float16)v2, (_Float16)v3};
                *(f16x4*)ob = pk;
            }
        }
    }
}

// ---- one layer: q-conv (blocks 0..255) and k-conv (blocks 256..511) -------
template<bool L1>
__global__ __launch_bounds__(256)
void conv_pair_k(const _Float16* __restrict__ qin, const _Float16* __restrict__ kin,
                 const _Float16* __restrict__ wpq, const _Float16* __restrict__ wpk,
                 const float* __restrict__ bq, const float* __restrict__ bk,
                 void* __restrict__ qout, void* __restrict__ kout, float qoscale)
{
    __shared__ _Float16 smem[4 * 64 * 136];          // 69632 B (max of both)
    if (blockIdx.x < 256)
        conv_body<32, 32, 2, 2, 2, 2, L1, !L1>(qin, wpq, bq, qout, qoscale,
                                               blockIdx.x, smem);
    else
        conv_body<64, 64, 2, 1, 4, 4, L1, !L1>(kin, wpk, bk, kout, 1.f,
                                               blockIdx.x - 256, smem);
}

// ---------------------------------------------------------------------------
// MFMA flash attention, split-K 2-way (unchanged from round 5).
// ---------------------------------------------------------------------------
__global__ __launch_bounds__(512)
void attn_mfma_k(const _Float16* __restrict__ q, const _Float16* __restrict__ k,
                 const float* __restrict__ v, float* __restrict__ part)
{
    __shared__ float vs[2048];
    __shared__ float red[8][64][3];

    const int bx  = blockIdx.x;
    const int b   = bx & 7;                          // XCD-pinned batch
    const int qt  = (bx >> 3) & 15;
    const int kv  = bx >> 7;
    const int tid = threadIdx.x;
    const int wid = tid >> 6, lane = tid & 63;
    const int l15 = lane & 15, lg = lane >> 4;

    const _Float16* qb = q + ((size_t)b * 1024 + qt * 64) * 128;
    const _Float16* kb = k + ((size_t)b * 4096 + kv * 2048 + wid * 256) * 128;
    const float*    vb = v + (size_t)b * 4096 + kv * 2048;

    *(float4*)&vs[tid * 4] = *(const float4*)&vb[tid * 4];

    f16x8 qf[4][4];
#pragma unroll
    for (int qti = 0; qti < 4; ++qti)
#pragma unroll
        for (int cc = 0; cc < 4; ++cc)
            qf[qti][cc] = *(const f16x8*)(qb + (size_t)(qti * 16 + l15) * 128 + cc * 32 + lg * 8);
    __syncthreads();

    float m[4], num[4], den[4];
#pragma unroll
    for (int a = 0; a < 4; ++a) { m[a] = -1e30f; num[a] = 0.f; den[a] = 0.f; }

    f16x8 kf[2][4];
#pragma unroll
    for (int cc = 0; cc < 4; ++cc) {
        kf[0][cc] = *(const f16x8*)(kb + (size_t)(l15)      * 128 + cc * 32 + lg * 8);
        kf[1][cc] = *(const f16x8*)(kb + (size_t)(16 + l15) * 128 + cc * 32 + lg * 8);
    }

#pragma unroll
    for (int kt = 0; kt < 16; ++kt) {
        f32x4 acc[4] = {};
#pragma unroll
        for (int cc = 0; cc < 4; ++cc) {
#pragma unroll
            for (int qti = 0; qti < 4; ++qti)
                acc[qti] = __builtin_amdgcn_mfma_f32_16x16x32_f16(
                    kf[kt & 1][cc], qf[qti][cc], acc[qti], 0, 0, 0);
        }
        if (kt + 2 < 16) {
#pragma unroll
            for (int cc = 0; cc < 4; ++cc)
                kf[kt & 1][cc] = *(const f16x8*)(kb + (size_t)((kt + 2) * 16 + l15) * 128 + cc * 32 + lg * 8);
        }

        float4 vv = *(const float4*)&vs[wid * 256 + kt * 16 + lg * 4];
#pragma unroll
        for (int qti = 0; qti < 4; ++qti) {
            float s0 = acc[qti][0], s1 = acc[qti][1], s2 = acc[qti][2], s3 = acc[qti][3];
            float smax = fmaxf(fmaxf(s0, s1), fmaxf(s2, s3));
            float mn = fmaxf(m[qti], smax);
            float c0 = __expf(m[qti] - mn);
            float e0 = __expf(s0 - mn);
            float e1 = __expf(s1 - mn);
            float e2 = __expf(s2 - mn);
            float e3 = __expf(s3 - mn);
            num[qti] = num[qti] * c0 + e0 * vv.x + e1 * vv.y + e2 * vv.z + e3 * vv.w;
            den[qti] = den[qti] * c0 + ((e0 + e1) + (e2 + e3));
            m[qti]   = mn;
        }
    }

#pragma unroll
    for (int off = 16; off <= 32; off <<= 1) {
#pragma unroll
        for (int qti = 0; qti < 4; ++qti) {
            float mo = __shfl_xor(m[qti], off);
            float no = __shfl_xor(num[qti], off);
            float dd = __shfl_xor(den[qti], off);
            float mn = fmaxf(m[qti], mo);
            float c0 = __expf(m[qti] - mn);
            float c1 = __expf(mo - mn);
            num[qti] = num[qti] * c0 + no * c1;
            den[qti] = den[qti] * c0 + dd * c1;
            m[qti]   = mn;
        }
    }
    if (lg == 0) {
#pragma unroll
        for (int qti = 0; qti < 4; ++qti) {
            red[wid][qti * 16 + l15][0] = m[qti];
            red[wid][qti * 16 + l15][1] = num[qti];
            red[wid][qti * 16 + l15][2] = den[qti];
        }
    }
    __syncthreads();
    if (tid < 64) {
        float M = -1e30f, N = 0.f, D = 0.f;
#pragma unroll
        for (int w = 0; w < 8; ++w) {
            float mo = red[w][tid][0], no = red[w][tid][1], dd = red[w][tid][2];
            float mn = fmaxf(M, mo);
            float c0 = __expf(M - mn);
            float c1 = __expf(mo - mn);
            N = N * c0 + no * c1;
            D = D * c0 + dd * c1;
            M = mn;
        }
        float4 o = {M, N, D, 0.f};
        ((float4*)part)[((size_t)(b * 2 + kv)) * 1024 + qt * 64 + tid] = o;
    }
}

// ---- combine the 2 kv-half partials per q-row -----------------------------
__global__ __launch_bounds__(256)
void attn_fin_k(const float* __restrict__ part, float* __restrict__ out)
{
    int gid = blockIdx.x * 256 + threadIdx.x;        // 8192
    int b = gid >> 10, row = gid & 1023;
    const float4* p4 = (const float4*)part;
    float4 a = p4[(size_t)(b * 2 + 0) * 1024 + row];
    float4 c = p4[(size_t)(b * 2 + 1) * 1024 + row];
    float mn = fmaxf(a.x, c.x);
    float ea = __expf(a.x - mn), ec = __expf(c.x - mn);
    out[gid] = (a.y * ea + c.y * ec) / (a.z * ea + c.z * ec);
}

// ---------------------------------------------------------------------------
extern "C" void kernel_launch(void* const* d_in, const int* in_sizes, int n_in,
                              void* d_out, int out_size, void* d_ws, size_t ws_size,
                              hipStream_t stream)
{
    const float* x   = (const float*)d_in[0];
    const float* y   = (const float*)d_in[1];
    const float* z   = (const float*)d_in[2];
    const float* wq1 = (const float*)d_in[3];
    const float* bq1 = (const float*)d_in[4];
    const float* wq2 = (const float*)d_in[5];
    const float* bq2 = (const float*)d_in[6];
    const float* wk1 = (const float*)d_in[7];
    const float* bk1 = (const float*)d_in[8];
    const float* wk2 = (const float*)d_in[9];
    const float* bk2 = (const float*)d_in[10];

    char* w8 = (char*)d_ws;
    _Float16* xpe  = (_Float16*)(w8);                  // 2 MB  NHWC f16
    _Float16* ype  = (_Float16*)(w8 + (2u  << 20));    // 8 MB  NHWC f16
    _Float16* t1   = (_Float16*)(w8 + (10u << 20));    // 2 MB  NHWC f16
    _Float16* t2   = (_Float16*)(w8 + (12u << 20));    // 8 MB  NHWC f16
    _Float16* qbuf = (_Float16*)(w8 + (20u << 20));    // 2 MB  NCHW f16 (scaled)
    _Float16* kbuf = (_Float16*)(w8 + (22u << 20));    // 8 MB  NCHW f16
    _Float16* wp   = (_Float16*)(w8 + (30u << 20));    // 4 x 288 KB packs
    float*    part = (float*)   (w8 + (32u << 20));    // 256 KB partials

    const float scale = 0.08838834764831845f;          // 128^-0.5

    prep_k<<<928, 256, 0, stream>>>(x, y, wq1, wq2, wk1, wk2, xpe, ype, wp);

    conv_pair_k<true ><<<512, 256, 0, stream>>>(xpe, ype, wp, wp + 2 * 147456,
                                                bq1, bk1, t1, t2, 1.f);
    conv_pair_k<false><<<512, 256, 0, stream>>>(t1, t2, wp + 147456, wp + 3 * 147456,
                                                bq2, bk2, qbuf, kbuf, scale);

    attn_mfma_k<<<256, 512, 0, stream>>>(qbuf, kbuf, z, part);
    attn_fin_k<<<32, 256, 0, stream>>>(part, (float*)d_out);
}